// Round 12
// baseline (2752.527 us; speedup 1.0000x reference)
//
#include <hip/hip_runtime.h>
#include <math.h>

namespace {
constexpr int B = 8, T = 64, N = 2048, H = 64, F = 64, E = 32768, G = 192;
constexpr int BNH = B * N * H;     // 1048576
constexpr int NWELEM = N * G * H;  // 25165824 per weight tensor
constexpr int NBLK = 1024;         // persistent blocks, 2 nodes each
}

typedef __attribute__((ext_vector_type(8))) short bfrag;   // 8 bf16 = 4 VGPRs
typedef __attribute__((ext_vector_type(4))) float ffrag;   // 4 fp32 acc
typedef long f8frag;                                       // 8 fp8 = 2 VGPRs

#define MFMA(a, b, c)  __builtin_amdgcn_mfma_f32_16x16x32_bf16(a, b, c, 0, 0, 0)
#define MFMA8(a, b, c) __builtin_amdgcn_mfma_f32_16x16x32_fp8_fp8(a, b, c, 0, 0, 0)

// weight scale 32, activation scale 16 -> descale product
#define DS (1.f / 512.f)

__device__ __forceinline__ unsigned short f2bf(float f) {
  unsigned u = __float_as_uint(f);
  u += 0x7fffu + ((u >> 16) & 1u);   // RNE
  return (unsigned short)(u >> 16);
}
__device__ __forceinline__ float bf2f(unsigned short u) {
  return __uint_as_float(((unsigned)u) << 16);
}
// packed f32x2 -> bf16x2 in one VALU op (no builtin on gfx950; RNE)
__device__ __forceinline__ unsigned cvtpk_bf16(float lo, float hi) {
  unsigned r;
  asm("v_cvt_pk_bf16_f32 %0, %1, %2" : "=v"(r) : "v"(lo), "v"(hi));
  return r;
}
template<bool HI>
__device__ __forceinline__ unsigned cvtpk8(float a, float b, unsigned old) {
  return __builtin_amdgcn_cvt_pk_fp8_f32(a, b, old, HI);
}

// ---- software grid barrier, fully relaxed (no wbl2/inv anywhere) -----------
// Ordering contract: sc1 message stores complete at MALL before the leaf
// arrival issues (vmcnt(0) drain inside __syncthreads + program order).
// Readers use FRESH ring-buffer addresses each step, so no invalidate needed.
__device__ __forceinline__ void grid_bar(int* bar, int t) {
  __syncthreads();   // drains vmcnt: message stores are complete at MALL
  if (threadIdx.x == 0) {
    __hip_atomic_fetch_add(&bar[(blockIdx.x & 63) * 16], 1,
                           __ATOMIC_RELAXED, __HIP_MEMORY_SCOPE_AGENT);
  }
  if (blockIdx.x == 0) {
    if (threadIdx.x < 64) {
      while (__hip_atomic_load(&bar[threadIdx.x * 16],
                               __ATOMIC_RELAXED, __HIP_MEMORY_SCOPE_AGENT) < 16 * (t + 1))
        __builtin_amdgcn_s_sleep(1);
      if (threadIdx.x == 0)
        __hip_atomic_store(&bar[4096], t + 1, __ATOMIC_RELAXED, __HIP_MEMORY_SCOPE_AGENT);
    }
  } else if (threadIdx.x == 0) {
    while (__hip_atomic_load(&bar[4096], __ATOMIC_RELAXED, __HIP_MEMORY_SCOPE_AGENT) < t + 1)
      __builtin_amdgcn_s_sleep(2);
  }
  asm volatile("" ::: "memory");   // forbid hoisting next step's loads above the spin
  __syncthreads();
}

// ---------------- setup kernels ----------------

__global__ __launch_bounds__(256) void init_kernel(
    unsigned short* __restrict__ buf0, const float* __restrict__ b_msg,
    float* __restrict__ loss_acc, float* __restrict__ scal,
    int* __restrict__ deg, int* __restrict__ bar)
{
  int stride = gridDim.x * blockDim.x;
  for (int i = blockIdx.x * blockDim.x + threadIdx.x; i < BNH; i += stride) {
    buf0[i] = f2bf(b_msg[i & (H - 1)]);   // step-0 message = 0 @ W_msg + b_msg
    if (i < 8192) bar[i] = 0;
    if (i < N) { loss_acc[i] = 0.f; deg[i] = 0; }
    if (i < 16) scal[i] = 0.f;
  }
}

// W_ih/W_hh -> fp8 e4m3 (x32 prescale); W_mix/W_msg -> bf16
__global__ __launch_bounds__(256) void conv_kernel(
    const float* __restrict__ Wi, const float* __restrict__ Wh,
    const float* __restrict__ Wm, const float* __restrict__ Wg,
    unsigned char* __restrict__ Wib, unsigned char* __restrict__ Whb,
    unsigned short* __restrict__ Wmb, unsigned short* __restrict__ Wgb)
{
  int stride = gridDim.x * blockDim.x * 2;
  for (int i = (blockIdx.x * blockDim.x + threadIdx.x) * 2; i < NWELEM; i += stride) {
    unsigned p = cvtpk8<false>(Wi[i] * 32.f, Wi[i + 1] * 32.f, 0u);
    *(unsigned short*)(Wib + i) = (unsigned short)p;
    p = cvtpk8<false>(Wh[i] * 32.f, Wh[i + 1] * 32.f, 0u);
    *(unsigned short*)(Whb + i) = (unsigned short)p;
    if (i < 64 * 128) { Wmb[i] = f2bf(Wm[i]); Wmb[i + 1] = f2bf(Wm[i + 1]); }
    if (i < 64 * 64)  { Wgb[i] = f2bf(Wg[i]); Wgb[i + 1] = f2bf(Wg[i + 1]); }
  }
}

__global__ __launch_bounds__(256) void hist_kernel(const int* __restrict__ ei, int* __restrict__ deg) {
  int e = blockIdx.x * 256 + threadIdx.x;
  if (e < E) atomicAdd(&deg[ei[E + e]], 1);   // row 1 = dst
}

__global__ __launch_bounds__(1024) void scan_kernel(const int* __restrict__ deg,
    int* __restrict__ row_ptr, int* __restrict__ cursor)
{
  __shared__ int s[N];
  int tid = threadIdx.x;
  s[tid] = deg[tid];
  s[tid + 1024] = deg[tid + 1024];
  __syncthreads();
  for (int off = 1; off < N; off <<= 1) {
    int v0 = (tid >= off) ? s[tid - off] : 0;
    int v1 = s[tid + 1024 - off];
    __syncthreads();
    s[tid] += v0;
    s[tid + 1024] += v1;
    __syncthreads();
  }
  row_ptr[tid + 1] = s[tid];
  row_ptr[tid + 1025] = s[tid + 1024];
  cursor[tid] = (tid == 0) ? 0 : s[tid - 1];
  cursor[tid + 1024] = s[tid + 1023];
  if (tid == 0) row_ptr[0] = 0;
}

__global__ __launch_bounds__(256) void fill_kernel(const int* __restrict__ ei,
    int* __restrict__ cursor, int* __restrict__ col_src)
{
  int e = blockIdx.x * 256 + threadIdx.x;
  if (e < E) {
    int d = ei[E + e];
    int slot = atomicAdd(&cursor[d], 1);
    col_src[slot] = ei[e];                  // row 0 = src
  }
}

__global__ __launch_bounds__(256) void mask_kernel(const int* __restrict__ mask, float* __restrict__ scal) {
  int stride = gridDim.x * blockDim.x;
  int v = 0;
  for (int i = blockIdx.x * blockDim.x + threadIdx.x; i < B * T * N; i += stride)
    v += (mask[i] != 0);
  for (int o = 1; o < 64; o <<= 1) v += __shfl_xor(v, o, 64);
  if ((threadIdx.x & 63) == 0) atomicAdd(&scal[0], (float)v);
}

// ---------------- persistent fused kernel ------------------------------------
// EXACT round-9 structure (best verified: profiled 1757 us / timed 2180 us).
// r10 (merged phases) and r11 (x-pipelining) both SPILLED (+16..56 live VGPRs
// across barriers at a full 128-reg budget). This round adds ONLY
// liveness-neutral VALU reductions: v_cvt_pk_bf16_f32 for x->bf16 (phase A,
// local), B1 partial repack (local), and phase-D message pack (local).
// Messages: 65-deep ring; step t reads buf[t] CACHED, writes buf[t+1] sc1.
// GRU weights + biases pinned in registers (opaque asm) for all T steps.

__global__ __attribute__((amdgpu_flat_work_group_size(256, 256), amdgpu_waves_per_eu(4, 4)))
void persist_kernel(
    const float* __restrict__ x, const float* __restrict__ targets,
    const int* __restrict__ mask,
    const unsigned char* __restrict__ W_ihb, const unsigned char* __restrict__ W_hhb,
    const unsigned short* __restrict__ W_mixb, const unsigned short* __restrict__ W_msgb,
    const float* __restrict__ b_ih, const float* __restrict__ b_hh,
    const float* __restrict__ b_mix, const float* __restrict__ b_msg,
    const float* __restrict__ W_read, const float* __restrict__ b_read,
    const int* __restrict__ row_ptr, const int* __restrict__ col_src,
    unsigned short* bufs,
    float* __restrict__ loss_acc, int* __restrict__ bar)
{
  __shared__ float sts[2][8][64];           // fp32 state, both nodes (persistent)
  __shared__ float partial[4][8][72];       // per-wave gather partials
  __shared__ unsigned char m2F8[8 * 80];    // m2 (x16) fp8
  __shared__ unsigned short nsA[8 * 72];    // new state bf16, A-layout
  __shared__ float redS[4][8];

  const int tid = threadIdx.x;
  const int w = tid >> 6, lane = tid & 63;
  const int mrow = lane & 15, quad = lane >> 4;
  const int n0 = blockIdx.x * 2;
  const bfrag za = (bfrag)0;
  const int hcol = w * 16 + mrow;

  // ---- one-time: GRU weights into registers (persist across T steps)
  f8frag whf[2][6], wif[2][6];
#pragma unroll
  for (int k = 0; k < 2; ++k) {
    const unsigned char* Wh = W_hhb + (size_t)(n0 + k) * (G * H);
    const unsigned char* Wi = W_ihb + (size_t)(n0 + k) * (G * H);
#pragma unroll
    for (int tt = 0; tt < 3; ++tt) {
      const int off = ((w + tt * 4) * 16 + mrow) * H + quad * 8;
      whf[k][2 * tt]     = *(const f8frag*)(Wh + off);
      whf[k][2 * tt + 1] = *(const f8frag*)(Wh + off + 32);
      wif[k][2 * tt]     = *(const f8frag*)(Wi + off);
      wif[k][2 * tt + 1] = *(const f8frag*)(Wi + off + 32);
    }
  }
  const unsigned short* wmp = W_mixb + hcol * 128 + quad * 8;
  const unsigned short* wgp = W_msgb + hcol * H + quad * 8;

  float bir[2], biz[2], bin_[2], bhr[2], bhz[2], bhn[2];
#pragma unroll
  for (int k = 0; k < 2; ++k) {
    const int bg = (n0 + k) * G + hcol;
    bir[k] = b_ih[bg]; biz[k] = b_ih[bg + 64]; bin_[k] = b_ih[bg + 128];
    bhr[k] = b_hh[bg]; bhz[k] = b_hh[bg + 64]; bhn[k] = b_hh[bg + 128];
  }
  float wrd = W_read[hcol];
  float bmix = b_mix[hcol];
  float bmsg = b_msg[hcol];
  const float brd = b_read[0];
  const int e0a = row_ptr[n0], e0b = row_ptr[n0 + 1], e0c = row_ptr[n0 + 2];

  // ---- PIN persistent values (non-rematerializable -> stay resident)
#pragma unroll
  for (int k = 0; k < 2; ++k) {
#pragma unroll
    for (int j = 0; j < 6; ++j) {
      asm volatile("" : "+v"(whf[k][j]));
      asm volatile("" : "+v"(wif[k][j]));
    }
    asm volatile("" : "+v"(bir[k]), "+v"(biz[k]), "+v"(bin_[k]),
                      "+v"(bhr[k]), "+v"(bhz[k]), "+v"(bhn[k]));
  }
  asm volatile("" : "+v"(wrd), "+v"(bmix), "+v"(bmsg));

  for (int i = tid; i < 2 * 8 * 64; i += 256) ((float*)sts)[i] = 0.f;
  __syncthreads();

  float lsum[2] = {0.f, 0.f};
  const unsigned short* mcur = bufs;         // ring: step t reads bufs + t*BNH
  unsigned short* mnxt = bufs + BNH;

#pragma unroll 1
  for (int t = 0; t < T; ++t) {
#pragma unroll
    for (int k = 0; k < 2; ++k) {
      const int nn = n0 + k;
      const int ee0 = k ? e0b : e0a;
      const int ee1 = k ? e0c : e0b;

      // ---- Phase A: W_mix frag loads (L2-warm); state->fp8; x->bf16; gather; gh
      bfrag wm0 = *(const bfrag*)(wmp);
      bfrag wm1 = *(const bfrag*)(wmp + 32);
      bfrag wm2 = *(const bfrag*)(wmp + 64);
      bfrag wm3 = *(const bfrag*)(wmp + 96);
      f8frag asF0 = 0, asF1 = 0;
      bfrag a2 = za, a3 = za;
      if (mrow < 8) {
        const float* sp = &sts[k][mrow][0];
        {
          float4 s0 = *(const float4*)(sp + quad * 8);
          float4 s1 = *(const float4*)(sp + quad * 8 + 4);
          unsigned u0 = 0, u1 = 0;
          u0 = cvtpk8<false>(s0.x * 16.f, s0.y * 16.f, u0);
          u0 = cvtpk8<true >(s0.z * 16.f, s0.w * 16.f, u0);
          u1 = cvtpk8<false>(s1.x * 16.f, s1.y * 16.f, u1);
          u1 = cvtpk8<true >(s1.z * 16.f, s1.w * 16.f, u1);
          asF0 = (f8frag)(((unsigned long long)u1 << 32) | u0);
          s0 = *(const float4*)(sp + 32 + quad * 8);
          s1 = *(const float4*)(sp + 32 + quad * 8 + 4);
          u0 = 0; u1 = 0;
          u0 = cvtpk8<false>(s0.x * 16.f, s0.y * 16.f, u0);
          u0 = cvtpk8<true >(s0.z * 16.f, s0.w * 16.f, u0);
          u1 = cvtpk8<false>(s1.x * 16.f, s1.y * 16.f, u1);
          u1 = cvtpk8<true >(s1.z * 16.f, s1.w * 16.f, u1);
          asF1 = (f8frag)(((unsigned long long)u1 << 32) | u0);
        }
        const float* xp = x + (((size_t)mrow * T + t) * N + nn) * F + quad * 8;
        {
          float4 t0 = *(const float4*)(xp);
          float4 t1 = *(const float4*)(xp + 4);
          float4 t2 = *(const float4*)(xp + 32);
          float4 t3 = *(const float4*)(xp + 36);
          union { bfrag b; unsigned u[4]; } c;
          c.u[0] = cvtpk_bf16(t0.x, t0.y); c.u[1] = cvtpk_bf16(t0.z, t0.w);
          c.u[2] = cvtpk_bf16(t1.x, t1.y); c.u[3] = cvtpk_bf16(t1.z, t1.w);
          a2 = c.b;
          c.u[0] = cvtpk_bf16(t2.x, t2.y); c.u[1] = cvtpk_bf16(t2.z, t2.w);
          c.u[2] = cvtpk_bf16(t3.x, t3.y); c.u[3] = cvtpk_bf16(t3.z, t3.w);
          a3 = c.b;
        }
      }
      {
        // gather via NORMAL cached loads (ring buffer -> fresh addresses, no
        // staleness; L2 captures the out-degree reuse)
        float accL[4] = {0.f,0.f,0.f,0.f}, accH[4] = {0.f,0.f,0.f,0.f};
        const int j = lane & 31, bh = lane >> 5;
        const unsigned* mcU = (const unsigned*)mcur;
        for (int e = ee0 + w; e < ee1; e += 4) {
          const unsigned* mp = mcU + (size_t)col_src[e] * 256 + bh * 32 + j;
#pragma unroll
          for (int bb = 0; bb < 4; ++bb) {
            unsigned v = mp[bb * 64];
            accL[bb] += bf2f((unsigned short)(v & 0xffffu));
            accH[bb] += bf2f((unsigned short)(v >> 16));
          }
        }
#pragma unroll
        for (int bb = 0; bb < 4; ++bb) {
          partial[w][bb * 2 + bh][2 * j]     = accL[bb];
          partial[w][bb * 2 + bh][2 * j + 1] = accH[bb];
        }
      }
      ffrag ah0 = {0.f,0.f,0.f,0.f}, ah1 = {0.f,0.f,0.f,0.f}, ah2 = {0.f,0.f,0.f,0.f};
      ah0 = MFMA8(asF0, whf[k][0], ah0); ah0 = MFMA8(asF1, whf[k][1], ah0);
      ah1 = MFMA8(asF0, whf[k][2], ah1); ah1 = MFMA8(asF1, whf[k][3], ah1);
      ah2 = MFMA8(asF0, whf[k][4], ah2); ah2 = MFMA8(asF1, whf[k][5], ah2);
      __syncthreads();

      // ---- Phase B1: m2 = W_mix @ [agg; x] + b_mix -> fp8 LDS
      {
        bfrag a0 = za, a1 = za;
        if (mrow < 8) {
          union { bfrag b; unsigned u[4]; } c0, c1;
          const float* p = &partial[0][mrow][quad * 8];
          const float* p2 = &partial[0][mrow][32 + quad * 8];
#pragma unroll
          for (int j = 0; j < 4; ++j) {
            float sa = p[2*j]   + p[2*j+576]   + p[2*j+1152]   + p[2*j+1728];
            float sb = p[2*j+1] + p[2*j+1+576] + p[2*j+1+1152] + p[2*j+1+1728];
            c0.u[j] = cvtpk_bf16(sa, sb);
            float ta = p2[2*j]   + p2[2*j+576]   + p2[2*j+1152]   + p2[2*j+1728];
            float tb = p2[2*j+1] + p2[2*j+1+576] + p2[2*j+1+1152] + p2[2*j+1+1728];
            c1.u[j] = cvtpk_bf16(ta, tb);
          }
          a0 = c0.b; a1 = c1.b;
        }
        ffrag accm = {0.f, 0.f, 0.f, 0.f};
        accm = MFMA(a0, wm0, accm);
        accm = MFMA(a1, wm1, accm);
        accm = MFMA(a2, wm2, accm);
        accm = MFMA(a3, wm3, accm);
        if (quad < 2) {
#pragma unroll
          for (int r = 0; r < 4; ++r) {
            unsigned p = cvtpk8<false>((accm[r] + bmix) * 16.f, 0.f, 0u);
            m2F8[(quad * 4 + r) * 80 + hcol] = (unsigned char)(p & 0xffu);
          }
        }
      }
      __syncthreads();

      // ---- Phase B2 + C: gi MFMAs; GRU pointwise
      bfrag wg0 = *(const bfrag*)(wgp);
      bfrag wg1 = *(const bfrag*)(wgp + 32);
      {
        f8frag amF0 = 0, amF1 = 0;
        if (mrow < 8) {
          amF0 = *(const f8frag*)&m2F8[mrow * 80 + quad * 8];
          amF1 = *(const f8frag*)&m2F8[mrow * 80 + 32 + quad * 8];
        }
        ffrag ai0 = {0.f,0.f,0.f,0.f}, ai1 = {0.f,0.f,0.f,0.f}, ai2 = {0.f,0.f,0.f,0.f};
        ai0 = MFMA8(amF0, wif[k][0], ai0); ai0 = MFMA8(amF1, wif[k][1], ai0);
        ai1 = MFMA8(amF0, wif[k][2], ai1); ai1 = MFMA8(amF1, wif[k][3], ai1);
        ai2 = MFMA8(amF0, wif[k][4], ai2); ai2 = MFMA8(amF1, wif[k][5], ai2);
        if (quad < 2) {
          float v[4];
#pragma unroll
          for (int r = 0; r < 4; ++r) {
            const int b = quad * 4 + r;
            float rs  = (ai0[r] + ah0[r]) * DS + bir[k] + bhr[k];
            float zs  = (ai1[r] + ah1[r]) * DS + biz[k] + bhz[k];
            float in_ = ai2[r] * DS + bin_[k];
            float hn  = ah2[r] * DS + bhn[k];
            float rg = 1.f / (1.f + __expf(-rs));
            float z  = 1.f / (1.f + __expf(-zs));
            float pre = in_ + rg * hn;
            float a = __expf(-2.f * fabsf(pre));
            float nc = copysignf((1.f - a) / (1.f + a), pre);   // stable tanh
            float sold = sts[k][b][hcol];
            float ns = (1.f - z) * nc + z * sold;
            sts[k][b][hcol] = ns;
            nsA[b * 72 + hcol] = f2bf(ns);
            v[r] = ns * wrd;
          }
#pragma unroll
          for (int o = 1; o < 16; o <<= 1) {
#pragma unroll
            for (int r = 0; r < 4; ++r) v[r] += __shfl_xor(v[r], o, 64);
          }
          if (mrow == 0) {
#pragma unroll
            for (int r = 0; r < 4; ++r) redS[w][quad * 4 + r] = v[r];
          }
        }
      }
      __syncthreads();

      // ---- Phase D: m_next = W_msg @ ns + b_msg; sc1 packed stores to ring
      {
        bfrag an0 = za, an1 = za;
        if (mrow < 8) {
          an0 = *(const bfrag*)&nsA[mrow * 72 + quad * 8];
          an1 = *(const bfrag*)&nsA[mrow * 72 + 32 + quad * 8];
        }
        ffrag accg = {0.f, 0.f, 0.f, 0.f};
        accg = MFMA(an0, wg0, accg);
        accg = MFMA(an1, wg1, accg);
        if (quad < 2) {
          unsigned* mnU = (unsigned*)mnxt;
          const int jcol = hcol >> 1;
#pragma unroll
          for (int r = 0; r < 4; ++r) {
            float v0 = accg[r] + bmsg;
            float v1 = __shfl_xor(v0, 1, 64);    // partner (mrow^1) value
            if (!(mrow & 1)) {
              unsigned pk = cvtpk_bf16(v0, v1);
              __hip_atomic_store(&mnU[(size_t)nn * 256 + (quad * 4 + r) * 32 + jcol],
                                 pk, __ATOMIC_RELAXED, __HIP_MEMORY_SCOPE_AGENT);
            }
          }
        }
      }
      if (tid < 8) {
        float vv = redS[0][tid] + redS[1][tid] + redS[2][tid] + redS[3][tid] + brd;
        size_t idx = ((size_t)tid * T + t) * N + nn;
        float d = vv - targets[idx];
        float l = (mask[idx] != 0) ? 0.5f * d * d : 0.f;
        l += __shfl_xor(l, 1, 64);
        l += __shfl_xor(l, 2, 64);
        l += __shfl_xor(l, 4, 64);
        if (tid == 0) lsum[k] += l;
      }
    }
    grid_bar(bar, t);
    mcur = mnxt;          // ring advance: fresh addresses every step
    mnxt += BNH;
  }
  if (tid == 0) { loss_acc[n0] = lsum[0]; loss_acc[n0 + 1] = lsum[1]; }
}

__global__ __launch_bounds__(256) void final_kernel(const float* __restrict__ loss_acc,
    const float* __restrict__ scal, float* __restrict__ out)
{
  __shared__ float sred[4];
  float v = 0.f;
  for (int i = threadIdx.x; i < N; i += 256) v += loss_acc[i];
  for (int o = 1; o < 64; o <<= 1) v += __shfl_xor(v, o, 64);
  if ((threadIdx.x & 63) == 0) sred[threadIdx.x >> 6] = v;
  __syncthreads();
  if (threadIdx.x == 0) out[0] = (sred[0] + sred[1] + sred[2] + sred[3]) / scal[0];
}

extern "C" void kernel_launch(void* const* d_in, const int* in_sizes, int n_in,
                              void* d_out, int out_size, void* d_ws, size_t ws_size,
                              hipStream_t stream)
{
  const float* x       = (const float*)d_in[0];
  const float* targets = (const float*)d_in[1];
  const int*   mask    = (const int*)d_in[2];
  const int*   ei      = (const int*)d_in[3];
  const float* W_msg   = (const float*)d_in[4];
  const float* b_msg   = (const float*)d_in[5];
  const float* W_mix   = (const float*)d_in[6];
  const float* b_mix   = (const float*)d_in[7];
  const float* W_ih    = (const float*)d_in[8];
  const float* W_hh    = (const float*)d_in[9];
  const float* b_ih    = (const float*)d_in[10];
  const float* b_hh    = (const float*)d_in[11];
  const float* W_read  = (const float*)d_in[12];
  const float* b_read  = (const float*)d_in[13];
  float* out = (float*)d_out;

  unsigned short* bufs  = (unsigned short*)d_ws;            // ring: 65 x [N][B][H] bf16 = 136 MB
  float* loss_acc       = (float*)(bufs + (size_t)(T + 1) * BNH);
  float* scal           = loss_acc + N;
  int* deg              = (int*)(scal + 16);
  int* row_ptr          = deg + N;
  int* cursor           = row_ptr + (N + 16);
  int* col_src          = cursor + N;
  int* bar              = col_src + E;                      // 8192 ints (32 KB)
  unsigned char* W_ihb  = (unsigned char*)(bar + 8192);     // fp8, 24 MB (16B aligned)
  unsigned char* W_hhb  = W_ihb + NWELEM;                   // fp8, 24 MB
  unsigned short* W_mixb = (unsigned short*)(W_hhb + NWELEM);
  unsigned short* W_msgb = W_mixb + 64 * 128;
  // total ws use ~185 MB

  init_kernel<<<1024, 256, 0, stream>>>(bufs, b_msg, loss_acc, scal, deg, bar);
  conv_kernel<<<8192, 256, 0, stream>>>(W_ih, W_hh, W_mix, W_msg, W_ihb, W_hhb, W_mixb, W_msgb);
  hist_kernel<<<E / 256, 256, 0, stream>>>(ei, deg);
  scan_kernel<<<1, 1024, 0, stream>>>(deg, row_ptr, cursor);
  fill_kernel<<<E / 256, 256, 0, stream>>>(ei, cursor, col_src);
  mask_kernel<<<512, 256, 0, stream>>>(mask, scal);

  // Always persistent (graph-capture safe: no runtime HIP queries).
  persist_kernel<<<NBLK, 256, 0, stream>>>(x, targets, mask,
                                           W_ihb, W_hhb, W_mixb, W_msgb,
                                           b_ih, b_hh, b_mix, b_msg, W_read, b_read,
                                           row_ptr, col_src, bufs, loss_acc, bar);

  final_kernel<<<1, 256, 0, stream>>>(loss_acc, scal, out);
}

// Round 13
// 2179.513 us; speedup vs baseline: 1.2629x; 1.2629x over previous
//
#include <hip/hip_runtime.h>
#include <math.h>

namespace {
constexpr int B = 8, T = 64, N = 2048, H = 64, F = 64, E = 32768, G = 192;
constexpr int BNH = B * N * H;     // 1048576
constexpr int NWELEM = N * G * H;  // 25165824 per weight tensor
constexpr int NBLK = 1024;         // persistent blocks, 2 nodes each
}

typedef __attribute__((ext_vector_type(8))) short bfrag;   // 8 bf16 = 4 VGPRs
typedef __attribute__((ext_vector_type(4))) float ffrag;   // 4 fp32 acc
typedef long f8frag;                                       // 8 fp8 = 2 VGPRs

#define MFMA(a, b, c)  __builtin_amdgcn_mfma_f32_16x16x32_bf16(a, b, c, 0, 0, 0)
#define MFMA8(a, b, c) __builtin_amdgcn_mfma_f32_16x16x32_fp8_fp8(a, b, c, 0, 0, 0)

// weight scale 32, activation scale 16 -> descale product
#define DS (1.f / 512.f)

__device__ __forceinline__ unsigned short f2bf(float f) {
  unsigned u = __float_as_uint(f);
  u += 0x7fffu + ((u >> 16) & 1u);   // RNE
  return (unsigned short)(u >> 16);
}
__device__ __forceinline__ float bf2f(unsigned short u) {
  return __uint_as_float(((unsigned)u) << 16);
}
template<bool HI>
__device__ __forceinline__ unsigned cvtpk8(float a, float b, unsigned old) {
  return __builtin_amdgcn_cvt_pk_fp8_f32(a, b, old, HI);
}

// ---- software grid barrier, fully relaxed (no wbl2/inv anywhere) -----------
// Ordering contract: sc1 message stores complete at MALL before the leaf
// arrival issues (vmcnt(0) drain inside __syncthreads + program order).
// Readers use FRESH ring-buffer addresses each step, so no invalidate needed.
// 64 leaf counters (bar[l*16], 16 blocks each); block 0's wave 0 polls the 64
// leaves in parallel and publishes gen=t+1 at bar[4096]; others poll that word.
__device__ __forceinline__ void grid_bar(int* bar, int t) {
  __syncthreads();   // drains vmcnt: message stores are complete at MALL
  if (threadIdx.x == 0) {
    __hip_atomic_fetch_add(&bar[(blockIdx.x & 63) * 16], 1,
                           __ATOMIC_RELAXED, __HIP_MEMORY_SCOPE_AGENT);
  }
  if (blockIdx.x == 0) {
    if (threadIdx.x < 64) {
      while (__hip_atomic_load(&bar[threadIdx.x * 16],
                               __ATOMIC_RELAXED, __HIP_MEMORY_SCOPE_AGENT) < 16 * (t + 1))
        __builtin_amdgcn_s_sleep(1);
      if (threadIdx.x == 0)
        __hip_atomic_store(&bar[4096], t + 1, __ATOMIC_RELAXED, __HIP_MEMORY_SCOPE_AGENT);
    }
  } else if (threadIdx.x == 0) {
    while (__hip_atomic_load(&bar[4096], __ATOMIC_RELAXED, __HIP_MEMORY_SCOPE_AGENT) < t + 1)
      __builtin_amdgcn_s_sleep(2);
  }
  asm volatile("" ::: "memory");   // forbid hoisting next step's loads above the spin
  __syncthreads();
}

// ---------------- setup kernels ----------------

__global__ __launch_bounds__(256) void init_kernel(
    unsigned short* __restrict__ buf0, const float* __restrict__ b_msg,
    float* __restrict__ loss_acc, float* __restrict__ scal,
    int* __restrict__ deg, int* __restrict__ bar)
{
  int stride = gridDim.x * blockDim.x;
  for (int i = blockIdx.x * blockDim.x + threadIdx.x; i < BNH; i += stride) {
    buf0[i] = f2bf(b_msg[i & (H - 1)]);   // step-0 message = 0 @ W_msg + b_msg
    if (i < 8192) bar[i] = 0;
    if (i < N) { loss_acc[i] = 0.f; deg[i] = 0; }
    if (i < 16) scal[i] = 0.f;
  }
}

// W_ih/W_hh -> fp8 e4m3 (x32 prescale); W_mix/W_msg -> bf16
__global__ __launch_bounds__(256) void conv_kernel(
    const float* __restrict__ Wi, const float* __restrict__ Wh,
    const float* __restrict__ Wm, const float* __restrict__ Wg,
    unsigned char* __restrict__ Wib, unsigned char* __restrict__ Whb,
    unsigned short* __restrict__ Wmb, unsigned short* __restrict__ Wgb)
{
  int stride = gridDim.x * blockDim.x * 2;
  for (int i = (blockIdx.x * blockDim.x + threadIdx.x) * 2; i < NWELEM; i += stride) {
    unsigned p = cvtpk8<false>(Wi[i] * 32.f, Wi[i + 1] * 32.f, 0u);
    *(unsigned short*)(Wib + i) = (unsigned short)p;
    p = cvtpk8<false>(Wh[i] * 32.f, Wh[i + 1] * 32.f, 0u);
    *(unsigned short*)(Whb + i) = (unsigned short)p;
    if (i < 64 * 128) { Wmb[i] = f2bf(Wm[i]); Wmb[i + 1] = f2bf(Wm[i + 1]); }
    if (i < 64 * 64)  { Wgb[i] = f2bf(Wg[i]); Wgb[i + 1] = f2bf(Wg[i + 1]); }
  }
}

__global__ __launch_bounds__(256) void hist_kernel(const int* __restrict__ ei, int* __restrict__ deg) {
  int e = blockIdx.x * 256 + threadIdx.x;
  if (e < E) atomicAdd(&deg[ei[E + e]], 1);   // row 1 = dst
}

__global__ __launch_bounds__(1024) void scan_kernel(const int* __restrict__ deg,
    int* __restrict__ row_ptr, int* __restrict__ cursor)
{
  __shared__ int s[N];
  int tid = threadIdx.x;
  s[tid] = deg[tid];
  s[tid + 1024] = deg[tid + 1024];
  __syncthreads();
  for (int off = 1; off < N; off <<= 1) {
    int v0 = (tid >= off) ? s[tid - off] : 0;
    int v1 = s[tid + 1024 - off];
    __syncthreads();
    s[tid] += v0;
    s[tid + 1024] += v1;
    __syncthreads();
  }
  row_ptr[tid + 1] = s[tid];
  row_ptr[tid + 1025] = s[tid + 1024];
  cursor[tid] = (tid == 0) ? 0 : s[tid - 1];
  cursor[tid + 1024] = s[tid + 1023];
  if (tid == 0) row_ptr[0] = 0;
}

__global__ __launch_bounds__(256) void fill_kernel(const int* __restrict__ ei,
    int* __restrict__ cursor, int* __restrict__ col_src)
{
  int e = blockIdx.x * 256 + threadIdx.x;
  if (e < E) {
    int d = ei[E + e];
    int slot = atomicAdd(&cursor[d], 1);
    col_src[slot] = ei[e];                  // row 0 = src
  }
}

__global__ __launch_bounds__(256) void mask_kernel(const int* __restrict__ mask, float* __restrict__ scal) {
  int stride = gridDim.x * blockDim.x;
  int v = 0;
  for (int i = blockIdx.x * blockDim.x + threadIdx.x; i < B * T * N; i += stride)
    v += (mask[i] != 0);
  for (int o = 1; o < 64; o <<= 1) v += __shfl_xor(v, o, 64);
  if ((threadIdx.x & 63) == 0) atomicAdd(&scal[0], (float)v);
}

// ---------------- persistent fused kernel ------------------------------------
// EXACT round-9 configuration (best verified: profiled 1757 us / timed 2180 us).
// Rounds 10/11/12 each modified this and each SPILLED (WRITE_SIZE 192 -> 635..
// 896 MB): the r9 allocation sits exactly at the 64-arch-VGPR cliff, and any
// added arch-register pressure (merged phases, pipelined x frags, or cvt_pk
// inline-asm operand clusters) crosses it. Reverted byte-for-byte.
// 1024 blocks x 256 thr (4 waves), 2 nodes/block, T-loop inside.
// Messages: 65-deep ring; step t reads buf[t] CACHED (fresh addresses -> no
// staleness, L2 captures out-degree reuse), writes buf[t+1] via sc1 (MALL).
// GRU weights + biases pinned in registers (opaque asm) for all T steps.

__global__ __attribute__((amdgpu_flat_work_group_size(256, 256), amdgpu_waves_per_eu(4, 4)))
void persist_kernel(
    const float* __restrict__ x, const float* __restrict__ targets,
    const int* __restrict__ mask,
    const unsigned char* __restrict__ W_ihb, const unsigned char* __restrict__ W_hhb,
    const unsigned short* __restrict__ W_mixb, const unsigned short* __restrict__ W_msgb,
    const float* __restrict__ b_ih, const float* __restrict__ b_hh,
    const float* __restrict__ b_mix, const float* __restrict__ b_msg,
    const float* __restrict__ W_read, const float* __restrict__ b_read,
    const int* __restrict__ row_ptr, const int* __restrict__ col_src,
    unsigned short* bufs,
    float* __restrict__ loss_acc, int* __restrict__ bar)
{
  __shared__ float sts[2][8][64];           // fp32 state, both nodes (persistent)
  __shared__ float partial[4][8][72];       // per-wave gather partials
  __shared__ unsigned char m2F8[8 * 80];    // m2 (x16) fp8
  __shared__ unsigned short nsA[8 * 72];    // new state bf16, A-layout
  __shared__ float redS[4][8];

  const int tid = threadIdx.x;
  const int w = tid >> 6, lane = tid & 63;
  const int mrow = lane & 15, quad = lane >> 4;
  const int n0 = blockIdx.x * 2;
  const bfrag za = (bfrag)0;
  const int hcol = w * 16 + mrow;

  // ---- one-time: GRU weights into registers (persist across T steps)
  f8frag whf[2][6], wif[2][6];
#pragma unroll
  for (int k = 0; k < 2; ++k) {
    const unsigned char* Wh = W_hhb + (size_t)(n0 + k) * (G * H);
    const unsigned char* Wi = W_ihb + (size_t)(n0 + k) * (G * H);
#pragma unroll
    for (int tt = 0; tt < 3; ++tt) {
      const int off = ((w + tt * 4) * 16 + mrow) * H + quad * 8;
      whf[k][2 * tt]     = *(const f8frag*)(Wh + off);
      whf[k][2 * tt + 1] = *(const f8frag*)(Wh + off + 32);
      wif[k][2 * tt]     = *(const f8frag*)(Wi + off);
      wif[k][2 * tt + 1] = *(const f8frag*)(Wi + off + 32);
    }
  }
  const unsigned short* wmp = W_mixb + hcol * 128 + quad * 8;
  const unsigned short* wgp = W_msgb + hcol * H + quad * 8;

  float bir[2], biz[2], bin_[2], bhr[2], bhz[2], bhn[2];
#pragma unroll
  for (int k = 0; k < 2; ++k) {
    const int bg = (n0 + k) * G + hcol;
    bir[k] = b_ih[bg]; biz[k] = b_ih[bg + 64]; bin_[k] = b_ih[bg + 128];
    bhr[k] = b_hh[bg]; bhz[k] = b_hh[bg + 64]; bhn[k] = b_hh[bg + 128];
  }
  float wrd = W_read[hcol];
  float bmix = b_mix[hcol];
  float bmsg = b_msg[hcol];
  const float brd = b_read[0];
  const int e0a = row_ptr[n0], e0b = row_ptr[n0 + 1], e0c = row_ptr[n0 + 2];

  // ---- PIN persistent values (non-rematerializable -> stay resident)
#pragma unroll
  for (int k = 0; k < 2; ++k) {
#pragma unroll
    for (int j = 0; j < 6; ++j) {
      asm volatile("" : "+v"(whf[k][j]));
      asm volatile("" : "+v"(wif[k][j]));
    }
    asm volatile("" : "+v"(bir[k]), "+v"(biz[k]), "+v"(bin_[k]),
                      "+v"(bhr[k]), "+v"(bhz[k]), "+v"(bhn[k]));
  }
  asm volatile("" : "+v"(wrd), "+v"(bmix), "+v"(bmsg));

  for (int i = tid; i < 2 * 8 * 64; i += 256) ((float*)sts)[i] = 0.f;
  __syncthreads();

  float lsum[2] = {0.f, 0.f};
  const unsigned short* mcur = bufs;         // ring: step t reads bufs + t*BNH
  unsigned short* mnxt = bufs + BNH;

#pragma unroll 1
  for (int t = 0; t < T; ++t) {
#pragma unroll
    for (int k = 0; k < 2; ++k) {
      const int nn = n0 + k;
      const int ee0 = k ? e0b : e0a;
      const int ee1 = k ? e0c : e0b;

      // ---- Phase A: W_mix frag loads (L2-warm); state->fp8; x->bf16; gather; gh
      bfrag wm0 = *(const bfrag*)(wmp);
      bfrag wm1 = *(const bfrag*)(wmp + 32);
      bfrag wm2 = *(const bfrag*)(wmp + 64);
      bfrag wm3 = *(const bfrag*)(wmp + 96);
      f8frag asF0 = 0, asF1 = 0;
      bfrag a2 = za, a3 = za;
      if (mrow < 8) {
        const float* sp = &sts[k][mrow][0];
        {
          float4 s0 = *(const float4*)(sp + quad * 8);
          float4 s1 = *(const float4*)(sp + quad * 8 + 4);
          unsigned u0 = 0, u1 = 0;
          u0 = cvtpk8<false>(s0.x * 16.f, s0.y * 16.f, u0);
          u0 = cvtpk8<true >(s0.z * 16.f, s0.w * 16.f, u0);
          u1 = cvtpk8<false>(s1.x * 16.f, s1.y * 16.f, u1);
          u1 = cvtpk8<true >(s1.z * 16.f, s1.w * 16.f, u1);
          asF0 = (f8frag)(((unsigned long long)u1 << 32) | u0);
          s0 = *(const float4*)(sp + 32 + quad * 8);
          s1 = *(const float4*)(sp + 32 + quad * 8 + 4);
          u0 = 0; u1 = 0;
          u0 = cvtpk8<false>(s0.x * 16.f, s0.y * 16.f, u0);
          u0 = cvtpk8<true >(s0.z * 16.f, s0.w * 16.f, u0);
          u1 = cvtpk8<false>(s1.x * 16.f, s1.y * 16.f, u1);
          u1 = cvtpk8<true >(s1.z * 16.f, s1.w * 16.f, u1);
          asF1 = (f8frag)(((unsigned long long)u1 << 32) | u0);
        }
        const float* xp = x + (((size_t)mrow * T + t) * N + nn) * F;
        {
          float4 t0 = *(const float4*)(xp + quad * 8);
          float4 t1 = *(const float4*)(xp + quad * 8 + 4);
          a2[0]=(short)f2bf(t0.x); a2[1]=(short)f2bf(t0.y); a2[2]=(short)f2bf(t0.z); a2[3]=(short)f2bf(t0.w);
          a2[4]=(short)f2bf(t1.x); a2[5]=(short)f2bf(t1.y); a2[6]=(short)f2bf(t1.z); a2[7]=(short)f2bf(t1.w);
          t0 = *(const float4*)(xp + 32 + quad * 8);
          t1 = *(const float4*)(xp + 32 + quad * 8 + 4);
          a3[0]=(short)f2bf(t0.x); a3[1]=(short)f2bf(t0.y); a3[2]=(short)f2bf(t0.z); a3[3]=(short)f2bf(t0.w);
          a3[4]=(short)f2bf(t1.x); a3[5]=(short)f2bf(t1.y); a3[6]=(short)f2bf(t1.z); a3[7]=(short)f2bf(t1.w);
        }
      }
      {
        // gather via NORMAL cached loads (ring buffer -> fresh addresses, no
        // staleness; L2 captures the out-degree reuse that sc1 loads wasted)
        float accL[4] = {0.f,0.f,0.f,0.f}, accH[4] = {0.f,0.f,0.f,0.f};
        const int j = lane & 31, bh = lane >> 5;
        const unsigned* mcU = (const unsigned*)mcur;
        for (int e = ee0 + w; e < ee1; e += 4) {
          const unsigned* mp = mcU + (size_t)col_src[e] * 256 + bh * 32 + j;
#pragma unroll
          for (int bb = 0; bb < 4; ++bb) {
            unsigned v = mp[bb * 64];
            accL[bb] += bf2f((unsigned short)(v & 0xffffu));
            accH[bb] += bf2f((unsigned short)(v >> 16));
          }
        }
#pragma unroll
        for (int bb = 0; bb < 4; ++bb) {
          partial[w][bb * 2 + bh][2 * j]     = accL[bb];
          partial[w][bb * 2 + bh][2 * j + 1] = accH[bb];
        }
      }
      ffrag ah0 = {0.f,0.f,0.f,0.f}, ah1 = {0.f,0.f,0.f,0.f}, ah2 = {0.f,0.f,0.f,0.f};
      ah0 = MFMA8(asF0, whf[k][0], ah0); ah0 = MFMA8(asF1, whf[k][1], ah0);
      ah1 = MFMA8(asF0, whf[k][2], ah1); ah1 = MFMA8(asF1, whf[k][3], ah1);
      ah2 = MFMA8(asF0, whf[k][4], ah2); ah2 = MFMA8(asF1, whf[k][5], ah2);
      __syncthreads();

      // ---- Phase B1: m2 = W_mix @ [agg; x] + b_mix -> fp8 LDS
      {
        bfrag a0 = za, a1 = za;
        if (mrow < 8) {
          const float* p = &partial[0][mrow][quad * 8];
#pragma unroll
          for (int j = 0; j < 8; ++j) {
            float s = p[j] + p[j + 576] + p[j + 1152] + p[j + 1728];
            a0[j] = (short)f2bf(s);
          }
          const float* p2 = &partial[0][mrow][32 + quad * 8];
#pragma unroll
          for (int j = 0; j < 8; ++j) {
            float s = p2[j] + p2[j + 576] + p2[j + 1152] + p2[j + 1728];
            a1[j] = (short)f2bf(s);
          }
        }
        ffrag accm = {0.f, 0.f, 0.f, 0.f};
        accm = MFMA(a0, wm0, accm);
        accm = MFMA(a1, wm1, accm);
        accm = MFMA(a2, wm2, accm);
        accm = MFMA(a3, wm3, accm);
        if (quad < 2) {
#pragma unroll
          for (int r = 0; r < 4; ++r) {
            unsigned p = cvtpk8<false>((accm[r] + bmix) * 16.f, 0.f, 0u);
            m2F8[(quad * 4 + r) * 80 + hcol] = (unsigned char)(p & 0xffu);
          }
        }
      }
      __syncthreads();

      // ---- Phase B2 + C: W_msg frag loads; gi MFMAs; GRU pointwise
      bfrag wg0 = *(const bfrag*)(wgp);
      bfrag wg1 = *(const bfrag*)(wgp + 32);
      {
        f8frag amF0 = 0, amF1 = 0;
        if (mrow < 8) {
          amF0 = *(const f8frag*)&m2F8[mrow * 80 + quad * 8];
          amF1 = *(const f8frag*)&m2F8[mrow * 80 + 32 + quad * 8];
        }
        ffrag ai0 = {0.f,0.f,0.f,0.f}, ai1 = {0.f,0.f,0.f,0.f}, ai2 = {0.f,0.f,0.f,0.f};
        ai0 = MFMA8(amF0, wif[k][0], ai0); ai0 = MFMA8(amF1, wif[k][1], ai0);
        ai1 = MFMA8(amF0, wif[k][2], ai1); ai1 = MFMA8(amF1, wif[k][3], ai1);
        ai2 = MFMA8(amF0, wif[k][4], ai2); ai2 = MFMA8(amF1, wif[k][5], ai2);
        if (quad < 2) {
          float v[4];
#pragma unroll
          for (int r = 0; r < 4; ++r) {
            const int b = quad * 4 + r;
            float rs  = (ai0[r] + ah0[r]) * DS + bir[k] + bhr[k];
            float zs  = (ai1[r] + ah1[r]) * DS + biz[k] + bhz[k];
            float in_ = ai2[r] * DS + bin_[k];
            float hn  = ah2[r] * DS + bhn[k];
            float rg = 1.f / (1.f + __expf(-rs));
            float z  = 1.f / (1.f + __expf(-zs));
            float pre = in_ + rg * hn;
            float a = __expf(-2.f * fabsf(pre));
            float nc = copysignf((1.f - a) / (1.f + a), pre);   // stable tanh
            float sold = sts[k][b][hcol];
            float ns = (1.f - z) * nc + z * sold;
            sts[k][b][hcol] = ns;
            nsA[b * 72 + hcol] = f2bf(ns);
            v[r] = ns * wrd;
          }
#pragma unroll
          for (int o = 1; o < 16; o <<= 1) {
#pragma unroll
            for (int r = 0; r < 4; ++r) v[r] += __shfl_xor(v[r], o, 64);
          }
          if (mrow == 0) {
#pragma unroll
            for (int r = 0; r < 4; ++r) redS[w][quad * 4 + r] = v[r];
          }
        }
      }
      __syncthreads();

      // ---- Phase D: m_next = W_msg @ ns + b_msg; sc1 packed stores to ring
      {
        bfrag an0 = za, an1 = za;
        if (mrow < 8) {
          an0 = *(const bfrag*)&nsA[mrow * 72 + quad * 8];
          an1 = *(const bfrag*)&nsA[mrow * 72 + 32 + quad * 8];
        }
        ffrag accg = {0.f, 0.f, 0.f, 0.f};
        accg = MFMA(an0, wg0, accg);
        accg = MFMA(an1, wg1, accg);
        if (quad < 2) {
          unsigned* mnU = (unsigned*)mnxt;
          const int jcol = hcol >> 1;
#pragma unroll
          for (int r = 0; r < 4; ++r) {
            float v0 = accg[r] + bmsg;
            float v1 = __shfl_xor(v0, 1, 64);    // partner (mrow^1) value
            if (!(mrow & 1)) {
              unsigned pk = (unsigned)f2bf(v0) | ((unsigned)f2bf(v1) << 16);
              __hip_atomic_store(&mnU[(size_t)nn * 256 + (quad * 4 + r) * 32 + jcol],
                                 pk, __ATOMIC_RELAXED, __HIP_MEMORY_SCOPE_AGENT);
            }
          }
        }
      }
      if (tid < 8) {
        float vv = redS[0][tid] + redS[1][tid] + redS[2][tid] + redS[3][tid] + brd;
        size_t idx = ((size_t)tid * T + t) * N + nn;
        float d = vv - targets[idx];
        float l = (mask[idx] != 0) ? 0.5f * d * d : 0.f;
        l += __shfl_xor(l, 1, 64);
        l += __shfl_xor(l, 2, 64);
        l += __shfl_xor(l, 4, 64);
        if (tid == 0) lsum[k] += l;
      }
    }
    grid_bar(bar, t);
    mcur = mnxt;          // ring advance: fresh addresses every step
    mnxt += BNH;
  }
  if (tid == 0) { loss_acc[n0] = lsum[0]; loss_acc[n0 + 1] = lsum[1]; }
}

__global__ __launch_bounds__(256) void final_kernel(const float* __restrict__ loss_acc,
    const float* __restrict__ scal, float* __restrict__ out)
{
  __shared__ float sred[4];
  float v = 0.f;
  for (int i = threadIdx.x; i < N; i += 256) v += loss_acc[i];
  for (int o = 1; o < 64; o <<= 1) v += __shfl_xor(v, o, 64);
  if ((threadIdx.x & 63) == 0) sred[threadIdx.x >> 6] = v;
  __syncthreads();
  if (threadIdx.x == 0) out[0] = (sred[0] + sred[1] + sred[2] + sred[3]) / scal[0];
}

extern "C" void kernel_launch(void* const* d_in, const int* in_sizes, int n_in,
                              void* d_out, int out_size, void* d_ws, size_t ws_size,
                              hipStream_t stream)
{
  const float* x       = (const float*)d_in[0];
  const float* targets = (const float*)d_in[1];
  const int*   mask    = (const int*)d_in[2];
  const int*   ei      = (const int*)d_in[3];
  const float* W_msg   = (const float*)d_in[4];
  const float* b_msg   = (const float*)d_in[5];
  const float* W_mix   = (const float*)d_in[6];
  const float* b_mix   = (const float*)d_in[7];
  const float* W_ih    = (const float*)d_in[8];
  const float* W_hh    = (const float*)d_in[9];
  const float* b_ih    = (const float*)d_in[10];
  const float* b_hh    = (const float*)d_in[11];
  const float* W_read  = (const float*)d_in[12];
  const float* b_read  = (const float*)d_in[13];
  float* out = (float*)d_out;

  unsigned short* bufs  = (unsigned short*)d_ws;            // ring: 65 x [N][B][H] bf16 = 136 MB
  float* loss_acc       = (float*)(bufs + (size_t)(T + 1) * BNH);
  float* scal           = loss_acc + N;
  int* deg              = (int*)(scal + 16);
  int* row_ptr          = deg + N;
  int* cursor           = row_ptr + (N + 16);
  int* col_src          = cursor + N;
  int* bar              = col_src + E;                      // 8192 ints (32 KB)
  unsigned char* W_ihb  = (unsigned char*)(bar + 8192);     // fp8, 24 MB (16B aligned)
  unsigned char* W_hhb  = W_ihb + NWELEM;                   // fp8, 24 MB
  unsigned short* W_mixb = (unsigned short*)(W_hhb + NWELEM);
  unsigned short* W_msgb = W_mixb + 64 * 128;
  // total ws use ~185 MB

  init_kernel<<<1024, 256, 0, stream>>>(bufs, b_msg, loss_acc, scal, deg, bar);
  conv_kernel<<<8192, 256, 0, stream>>>(W_ih, W_hh, W_mix, W_msg, W_ihb, W_hhb, W_mixb, W_msgb);
  hist_kernel<<<E / 256, 256, 0, stream>>>(ei, deg);
  scan_kernel<<<1, 1024, 0, stream>>>(deg, row_ptr, cursor);
  fill_kernel<<<E / 256, 256, 0, stream>>>(ei, cursor, col_src);
  mask_kernel<<<512, 256, 0, stream>>>(mask, scal);

  // Always persistent (graph-capture safe: no runtime HIP queries).
  persist_kernel<<<NBLK, 256, 0, stream>>>(x, targets, mask,
                                           W_ihb, W_hhb, W_mixb, W_msgb,
                                           b_ih, b_hh, b_mix, b_msg, W_read, b_read,
                                           row_ptr, col_src, bufs, loss_acc, bar);

  final_kernel<<<1, 256, 0, stream>>>(loss_acc, scal, out);
}

// Round 14
// 2178.580 us; speedup vs baseline: 1.2634x; 1.0004x over previous
//
#include <hip/hip_runtime.h>
#include <math.h>

namespace {
constexpr int B = 8, T = 64, N = 2048, H = 64, F = 64, E = 32768, G = 192;
constexpr int BNH = B * N * H;     // 1048576
constexpr int NWELEM = N * G * H;  // 25165824 per weight tensor
constexpr int NBLK = 1024;         // persistent blocks, 2 nodes each
}

typedef __attribute__((ext_vector_type(8))) short bfrag;   // 8 bf16 = 4 VGPRs
typedef __attribute__((ext_vector_type(4))) float ffrag;   // 4 fp32 acc
typedef long f8frag;                                       // 8 fp8 = 2 VGPRs

#define MFMA(a, b, c)  __builtin_amdgcn_mfma_f32_16x16x32_bf16(a, b, c, 0, 0, 0)
#define MFMA8(a, b, c) __builtin_amdgcn_mfma_f32_16x16x32_fp8_fp8(a, b, c, 0, 0, 0)

// weight scale 32, activation scale 16 -> descale product
#define DS (1.f / 512.f)

__device__ __forceinline__ unsigned short f2bf(float f) {
  unsigned u = __float_as_uint(f);
  u += 0x7fffu + ((u >> 16) & 1u);   // RNE
  return (unsigned short)(u >> 16);
}
__device__ __forceinline__ float bf2f(unsigned short u) {
  return __uint_as_float(((unsigned)u) << 16);
}
template<bool HI>
__device__ __forceinline__ unsigned cvtpk8(float a, float b, unsigned old) {
  return __builtin_amdgcn_cvt_pk_fp8_f32(a, b, old, HI);
}

// ---- software grid barrier, fully relaxed (no wbl2/inv anywhere) -----------
// Ordering contract: sc1 message stores complete at MALL before the leaf
// arrival issues (vmcnt(0) drain inside __syncthreads + program order).
// Readers use FRESH ring-buffer addresses each step, so no invalidate needed.
__device__ __forceinline__ void grid_bar(int* bar, int t) {
  __syncthreads();   // drains vmcnt: message stores are complete at MALL
  if (threadIdx.x == 0) {
    __hip_atomic_fetch_add(&bar[(blockIdx.x & 63) * 16], 1,
                           __ATOMIC_RELAXED, __HIP_MEMORY_SCOPE_AGENT);
  }
  if (blockIdx.x == 0) {
    if (threadIdx.x < 64) {
      while (__hip_atomic_load(&bar[threadIdx.x * 16],
                               __ATOMIC_RELAXED, __HIP_MEMORY_SCOPE_AGENT) < 16 * (t + 1))
        __builtin_amdgcn_s_sleep(1);
      if (threadIdx.x == 0)
        __hip_atomic_store(&bar[4096], t + 1, __ATOMIC_RELAXED, __HIP_MEMORY_SCOPE_AGENT);
    }
  } else if (threadIdx.x == 0) {
    while (__hip_atomic_load(&bar[4096], __ATOMIC_RELAXED, __HIP_MEMORY_SCOPE_AGENT) < t + 1)
      __builtin_amdgcn_s_sleep(2);
  }
  asm volatile("" ::: "memory");   // forbid hoisting next step's loads above the spin
  __syncthreads();
}

// ---------------- setup kernels ----------------

__global__ __launch_bounds__(256) void init_kernel(
    unsigned short* __restrict__ buf0, const float* __restrict__ b_msg,
    float* __restrict__ loss_acc, float* __restrict__ scal,
    int* __restrict__ deg, int* __restrict__ bar)
{
  int stride = gridDim.x * blockDim.x;
  for (int i = blockIdx.x * blockDim.x + threadIdx.x; i < BNH; i += stride) {
    buf0[i] = f2bf(b_msg[i & (H - 1)]);   // step-0 message = 0 @ W_msg + b_msg
    if (i < 8192) bar[i] = 0;
    if (i < N) { loss_acc[i] = 0.f; deg[i] = 0; }
    if (i < 16) scal[i] = 0.f;
  }
}

// W_ih/W_hh -> fp8 e4m3 (x32 prescale); W_mix/W_msg -> bf16
__global__ __launch_bounds__(256) void conv_kernel(
    const float* __restrict__ Wi, const float* __restrict__ Wh,
    const float* __restrict__ Wm, const float* __restrict__ Wg,
    unsigned char* __restrict__ Wib, unsigned char* __restrict__ Whb,
    unsigned short* __restrict__ Wmb, unsigned short* __restrict__ Wgb)
{
  int stride = gridDim.x * blockDim.x * 2;
  for (int i = (blockIdx.x * blockDim.x + threadIdx.x) * 2; i < NWELEM; i += stride) {
    unsigned p = cvtpk8<false>(Wi[i] * 32.f, Wi[i + 1] * 32.f, 0u);
    *(unsigned short*)(Wib + i) = (unsigned short)p;
    p = cvtpk8<false>(Wh[i] * 32.f, Wh[i + 1] * 32.f, 0u);
    *(unsigned short*)(Whb + i) = (unsigned short)p;
    if (i < 64 * 128) { Wmb[i] = f2bf(Wm[i]); Wmb[i + 1] = f2bf(Wm[i + 1]); }
    if (i < 64 * 64)  { Wgb[i] = f2bf(Wg[i]); Wgb[i + 1] = f2bf(Wg[i + 1]); }
  }
}

__global__ __launch_bounds__(256) void hist_kernel(const int* __restrict__ ei, int* __restrict__ deg) {
  int e = blockIdx.x * 256 + threadIdx.x;
  if (e < E) atomicAdd(&deg[ei[E + e]], 1);   // row 1 = dst
}

__global__ __launch_bounds__(1024) void scan_kernel(const int* __restrict__ deg,
    int* __restrict__ row_ptr, int* __restrict__ cursor)
{
  __shared__ int s[N];
  int tid = threadIdx.x;
  s[tid] = deg[tid];
  s[tid + 1024] = deg[tid + 1024];
  __syncthreads();
  for (int off = 1; off < N; off <<= 1) {
    int v0 = (tid >= off) ? s[tid - off] : 0;
    int v1 = s[tid + 1024 - off];
    __syncthreads();
    s[tid] += v0;
    s[tid + 1024] += v1;
    __syncthreads();
  }
  row_ptr[tid + 1] = s[tid];
  row_ptr[tid + 1025] = s[tid + 1024];
  cursor[tid] = (tid == 0) ? 0 : s[tid - 1];
  cursor[tid + 1024] = s[tid + 1023];
  if (tid == 0) row_ptr[0] = 0;
}

__global__ __launch_bounds__(256) void fill_kernel(const int* __restrict__ ei,
    int* __restrict__ cursor, int* __restrict__ col_src)
{
  int e = blockIdx.x * 256 + threadIdx.x;
  if (e < E) {
    int d = ei[E + e];
    int slot = atomicAdd(&cursor[d], 1);
    col_src[slot] = ei[e];                  // row 0 = src
  }
}

__global__ __launch_bounds__(256) void mask_kernel(const int* __restrict__ mask, float* __restrict__ scal) {
  int stride = gridDim.x * blockDim.x;
  int v = 0;
  for (int i = blockIdx.x * blockDim.x + threadIdx.x; i < B * T * N; i += stride)
    v += (mask[i] != 0);
  for (int o = 1; o < 64; o <<= 1) v += __shfl_xor(v, o, 64);
  if ((threadIdx.x & 63) == 0) atomicAdd(&scal[0], (float)v);
}

// ---------------- persistent fused kernel ------------------------------------
// Round-9 structure (best verified: profiled 1753 us / timed 2179 us),
// with one LIVENESS-REDUCING change: the W_mix fragment loads (16 VGPRs)
// move from phase A into their consuming phase B1, and the W_msg fragment
// loads (8 VGPRs) move from B2+C into phase D. Both were cross-barrier
// latency-hiding hoists inherited from the per-step kernel; the data is
// L2-warm (~200-500cy) and each consuming phase starts with longer LDS work
// that covers the latency. This relieves arch-VGPR pressure exactly at the
// phase-A peak region (r10/r11/r12 showed the allocation sits at the 64-reg
// cliff; this moves AWAY from the cliff - spill risk strictly decreases).
// Messages: 65-deep ring; step t reads buf[t] CACHED, writes buf[t+1] sc1.
// GRU weights + biases pinned in registers (opaque asm) for all T steps.

__global__ __attribute__((amdgpu_flat_work_group_size(256, 256), amdgpu_waves_per_eu(4, 4)))
void persist_kernel(
    const float* __restrict__ x, const float* __restrict__ targets,
    const int* __restrict__ mask,
    const unsigned char* __restrict__ W_ihb, const unsigned char* __restrict__ W_hhb,
    const unsigned short* __restrict__ W_mixb, const unsigned short* __restrict__ W_msgb,
    const float* __restrict__ b_ih, const float* __restrict__ b_hh,
    const float* __restrict__ b_mix, const float* __restrict__ b_msg,
    const float* __restrict__ W_read, const float* __restrict__ b_read,
    const int* __restrict__ row_ptr, const int* __restrict__ col_src,
    unsigned short* bufs,
    float* __restrict__ loss_acc, int* __restrict__ bar)
{
  __shared__ float sts[2][8][64];           // fp32 state, both nodes (persistent)
  __shared__ float partial[4][8][72];       // per-wave gather partials
  __shared__ unsigned char m2F8[8 * 80];    // m2 (x16) fp8
  __shared__ unsigned short nsA[8 * 72];    // new state bf16, A-layout
  __shared__ float redS[4][8];

  const int tid = threadIdx.x;
  const int w = tid >> 6, lane = tid & 63;
  const int mrow = lane & 15, quad = lane >> 4;
  const int n0 = blockIdx.x * 2;
  const bfrag za = (bfrag)0;
  const int hcol = w * 16 + mrow;

  // ---- one-time: GRU weights into registers (persist across T steps)
  f8frag whf[2][6], wif[2][6];
#pragma unroll
  for (int k = 0; k < 2; ++k) {
    const unsigned char* Wh = W_hhb + (size_t)(n0 + k) * (G * H);
    const unsigned char* Wi = W_ihb + (size_t)(n0 + k) * (G * H);
#pragma unroll
    for (int tt = 0; tt < 3; ++tt) {
      const int off = ((w + tt * 4) * 16 + mrow) * H + quad * 8;
      whf[k][2 * tt]     = *(const f8frag*)(Wh + off);
      whf[k][2 * tt + 1] = *(const f8frag*)(Wh + off + 32);
      wif[k][2 * tt]     = *(const f8frag*)(Wi + off);
      wif[k][2 * tt + 1] = *(const f8frag*)(Wi + off + 32);
    }
  }
  const unsigned short* wmp = W_mixb + hcol * 128 + quad * 8;
  const unsigned short* wgp = W_msgb + hcol * H + quad * 8;

  float bir[2], biz[2], bin_[2], bhr[2], bhz[2], bhn[2];
#pragma unroll
  for (int k = 0; k < 2; ++k) {
    const int bg = (n0 + k) * G + hcol;
    bir[k] = b_ih[bg]; biz[k] = b_ih[bg + 64]; bin_[k] = b_ih[bg + 128];
    bhr[k] = b_hh[bg]; bhz[k] = b_hh[bg + 64]; bhn[k] = b_hh[bg + 128];
  }
  float wrd = W_read[hcol];
  float bmix = b_mix[hcol];
  float bmsg = b_msg[hcol];
  const float brd = b_read[0];
  const int e0a = row_ptr[n0], e0b = row_ptr[n0 + 1], e0c = row_ptr[n0 + 2];

  // ---- PIN persistent values (non-rematerializable -> stay resident)
#pragma unroll
  for (int k = 0; k < 2; ++k) {
#pragma unroll
    for (int j = 0; j < 6; ++j) {
      asm volatile("" : "+v"(whf[k][j]));
      asm volatile("" : "+v"(wif[k][j]));
    }
    asm volatile("" : "+v"(bir[k]), "+v"(biz[k]), "+v"(bin_[k]),
                      "+v"(bhr[k]), "+v"(bhz[k]), "+v"(bhn[k]));
  }
  asm volatile("" : "+v"(wrd), "+v"(bmix), "+v"(bmsg));

  for (int i = tid; i < 2 * 8 * 64; i += 256) ((float*)sts)[i] = 0.f;
  __syncthreads();

  float lsum[2] = {0.f, 0.f};
  const unsigned short* mcur = bufs;         // ring: step t reads bufs + t*BNH
  unsigned short* mnxt = bufs + BNH;

#pragma unroll 1
  for (int t = 0; t < T; ++t) {
#pragma unroll
    for (int k = 0; k < 2; ++k) {
      const int nn = n0 + k;
      const int ee0 = k ? e0b : e0a;
      const int ee1 = k ? e0c : e0b;

      // ---- Phase A: state->fp8; x->bf16; gather; gh MFMAs
      f8frag asF0 = 0, asF1 = 0;
      bfrag a2 = za, a3 = za;
      if (mrow < 8) {
        const float* sp = &sts[k][mrow][0];
        {
          float4 s0 = *(const float4*)(sp + quad * 8);
          float4 s1 = *(const float4*)(sp + quad * 8 + 4);
          unsigned u0 = 0, u1 = 0;
          u0 = cvtpk8<false>(s0.x * 16.f, s0.y * 16.f, u0);
          u0 = cvtpk8<true >(s0.z * 16.f, s0.w * 16.f, u0);
          u1 = cvtpk8<false>(s1.x * 16.f, s1.y * 16.f, u1);
          u1 = cvtpk8<true >(s1.z * 16.f, s1.w * 16.f, u1);
          asF0 = (f8frag)(((unsigned long long)u1 << 32) | u0);
          s0 = *(const float4*)(sp + 32 + quad * 8);
          s1 = *(const float4*)(sp + 32 + quad * 8 + 4);
          u0 = 0; u1 = 0;
          u0 = cvtpk8<false>(s0.x * 16.f, s0.y * 16.f, u0);
          u0 = cvtpk8<true >(s0.z * 16.f, s0.w * 16.f, u0);
          u1 = cvtpk8<false>(s1.x * 16.f, s1.y * 16.f, u1);
          u1 = cvtpk8<true >(s1.z * 16.f, s1.w * 16.f, u1);
          asF1 = (f8frag)(((unsigned long long)u1 << 32) | u0);
        }
        const float* xp = x + (((size_t)mrow * T + t) * N + nn) * F;
        {
          float4 t0 = *(const float4*)(xp + quad * 8);
          float4 t1 = *(const float4*)(xp + quad * 8 + 4);
          a2[0]=(short)f2bf(t0.x); a2[1]=(short)f2bf(t0.y); a2[2]=(short)f2bf(t0.z); a2[3]=(short)f2bf(t0.w);
          a2[4]=(short)f2bf(t1.x); a2[5]=(short)f2bf(t1.y); a2[6]=(short)f2bf(t1.z); a2[7]=(short)f2bf(t1.w);
          t0 = *(const float4*)(xp + 32 + quad * 8);
          t1 = *(const float4*)(xp + 32 + quad * 8 + 4);
          a3[0]=(short)f2bf(t0.x); a3[1]=(short)f2bf(t0.y); a3[2]=(short)f2bf(t0.z); a3[3]=(short)f2bf(t0.w);
          a3[4]=(short)f2bf(t1.x); a3[5]=(short)f2bf(t1.y); a3[6]=(short)f2bf(t1.z); a3[7]=(short)f2bf(t1.w);
        }
      }
      {
        // gather via NORMAL cached loads (ring buffer -> fresh addresses, no
        // staleness; L2 captures the out-degree reuse)
        float accL[4] = {0.f,0.f,0.f,0.f}, accH[4] = {0.f,0.f,0.f,0.f};
        const int j = lane & 31, bh = lane >> 5;
        const unsigned* mcU = (const unsigned*)mcur;
        for (int e = ee0 + w; e < ee1; e += 4) {
          const unsigned* mp = mcU + (size_t)col_src[e] * 256 + bh * 32 + j;
#pragma unroll
          for (int bb = 0; bb < 4; ++bb) {
            unsigned v = mp[bb * 64];
            accL[bb] += bf2f((unsigned short)(v & 0xffffu));
            accH[bb] += bf2f((unsigned short)(v >> 16));
          }
        }
#pragma unroll
        for (int bb = 0; bb < 4; ++bb) {
          partial[w][bb * 2 + bh][2 * j]     = accL[bb];
          partial[w][bb * 2 + bh][2 * j + 1] = accH[bb];
        }
      }
      ffrag ah0 = {0.f,0.f,0.f,0.f}, ah1 = {0.f,0.f,0.f,0.f}, ah2 = {0.f,0.f,0.f,0.f};
      ah0 = MFMA8(asF0, whf[k][0], ah0); ah0 = MFMA8(asF1, whf[k][1], ah0);
      ah1 = MFMA8(asF0, whf[k][2], ah1); ah1 = MFMA8(asF1, whf[k][3], ah1);
      ah2 = MFMA8(asF0, whf[k][4], ah2); ah2 = MFMA8(asF1, whf[k][5], ah2);
      __syncthreads();

      // ---- Phase B1: W_mix frag loads (L2-warm, covered by LDS repack);
      //               m2 = W_mix @ [agg; x] + b_mix -> fp8 LDS
      {
        bfrag wm0 = *(const bfrag*)(wmp);
        bfrag wm1 = *(const bfrag*)(wmp + 32);
        bfrag wm2 = *(const bfrag*)(wmp + 64);
        bfrag wm3 = *(const bfrag*)(wmp + 96);
        bfrag a0 = za, a1 = za;
        if (mrow < 8) {
          const float* p = &partial[0][mrow][quad * 8];
#pragma unroll
          for (int j = 0; j < 8; ++j) {
            float s = p[j] + p[j + 576] + p[j + 1152] + p[j + 1728];
            a0[j] = (short)f2bf(s);
          }
          const float* p2 = &partial[0][mrow][32 + quad * 8];
#pragma unroll
          for (int j = 0; j < 8; ++j) {
            float s = p2[j] + p2[j + 576] + p2[j + 1152] + p2[j + 1728];
            a1[j] = (short)f2bf(s);
          }
        }
        ffrag accm = {0.f, 0.f, 0.f, 0.f};
        accm = MFMA(a0, wm0, accm);
        accm = MFMA(a1, wm1, accm);
        accm = MFMA(a2, wm2, accm);
        accm = MFMA(a3, wm3, accm);
        if (quad < 2) {
#pragma unroll
          for (int r = 0; r < 4; ++r) {
            unsigned p = cvtpk8<false>((accm[r] + bmix) * 16.f, 0.f, 0u);
            m2F8[(quad * 4 + r) * 80 + hcol] = (unsigned char)(p & 0xffu);
          }
        }
      }
      __syncthreads();

      // ---- Phase B2 + C: gi MFMAs; GRU pointwise
      {
        f8frag amF0 = 0, amF1 = 0;
        if (mrow < 8) {
          amF0 = *(const f8frag*)&m2F8[mrow * 80 + quad * 8];
          amF1 = *(const f8frag*)&m2F8[mrow * 80 + 32 + quad * 8];
        }
        ffrag ai0 = {0.f,0.f,0.f,0.f}, ai1 = {0.f,0.f,0.f,0.f}, ai2 = {0.f,0.f,0.f,0.f};
        ai0 = MFMA8(amF0, wif[k][0], ai0); ai0 = MFMA8(amF1, wif[k][1], ai0);
        ai1 = MFMA8(amF0, wif[k][2], ai1); ai1 = MFMA8(amF1, wif[k][3], ai1);
        ai2 = MFMA8(amF0, wif[k][4], ai2); ai2 = MFMA8(amF1, wif[k][5], ai2);
        if (quad < 2) {
          float v[4];
#pragma unroll
          for (int r = 0; r < 4; ++r) {
            const int b = quad * 4 + r;
            float rs  = (ai0[r] + ah0[r]) * DS + bir[k] + bhr[k];
            float zs  = (ai1[r] + ah1[r]) * DS + biz[k] + bhz[k];
            float in_ = ai2[r] * DS + bin_[k];
            float hn  = ah2[r] * DS + bhn[k];
            float rg = 1.f / (1.f + __expf(-rs));
            float z  = 1.f / (1.f + __expf(-zs));
            float pre = in_ + rg * hn;
            float a = __expf(-2.f * fabsf(pre));
            float nc = copysignf((1.f - a) / (1.f + a), pre);   // stable tanh
            float sold = sts[k][b][hcol];
            float ns = (1.f - z) * nc + z * sold;
            sts[k][b][hcol] = ns;
            nsA[b * 72 + hcol] = f2bf(ns);
            v[r] = ns * wrd;
          }
#pragma unroll
          for (int o = 1; o < 16; o <<= 1) {
#pragma unroll
            for (int r = 0; r < 4; ++r) v[r] += __shfl_xor(v[r], o, 64);
          }
          if (mrow == 0) {
#pragma unroll
            for (int r = 0; r < 4; ++r) redS[w][quad * 4 + r] = v[r];
          }
        }
      }
      __syncthreads();

      // ---- Phase D: W_msg frag loads (covered by nsA LDS reads);
      //               m_next = W_msg @ ns + b_msg; sc1 packed stores to ring
      {
        bfrag wg0 = *(const bfrag*)(wgp);
        bfrag wg1 = *(const bfrag*)(wgp + 32);
        bfrag an0 = za, an1 = za;
        if (mrow < 8) {
          an0 = *(const bfrag*)&nsA[mrow * 72 + quad * 8];
          an1 = *(const bfrag*)&nsA[mrow * 72 + 32 + quad * 8];
        }
        ffrag accg = {0.f, 0.f, 0.f, 0.f};
        accg = MFMA(an0, wg0, accg);
        accg = MFMA(an1, wg1, accg);
        if (quad < 2) {
          unsigned* mnU = (unsigned*)mnxt;
          const int jcol = hcol >> 1;
#pragma unroll
          for (int r = 0; r < 4; ++r) {
            float v0 = accg[r] + bmsg;
            float v1 = __shfl_xor(v0, 1, 64);    // partner (mrow^1) value
            if (!(mrow & 1)) {
              unsigned pk = (unsigned)f2bf(v0) | ((unsigned)f2bf(v1) << 16);
              __hip_atomic_store(&mnU[(size_t)nn * 256 + (quad * 4 + r) * 32 + jcol],
                                 pk, __ATOMIC_RELAXED, __HIP_MEMORY_SCOPE_AGENT);
            }
          }
        }
      }
      if (tid < 8) {
        float vv = redS[0][tid] + redS[1][tid] + redS[2][tid] + redS[3][tid] + brd;
        size_t idx = ((size_t)tid * T + t) * N + nn;
        float d = vv - targets[idx];
        float l = (mask[idx] != 0) ? 0.5f * d * d : 0.f;
        l += __shfl_xor(l, 1, 64);
        l += __shfl_xor(l, 2, 64);
        l += __shfl_xor(l, 4, 64);
        if (tid == 0) lsum[k] += l;
      }
    }
    grid_bar(bar, t);
    mcur = mnxt;          // ring advance: fresh addresses every step
    mnxt += BNH;
  }
  if (tid == 0) { loss_acc[n0] = lsum[0]; loss_acc[n0 + 1] = lsum[1]; }
}

__global__ __launch_bounds__(256) void final_kernel(const float* __restrict__ loss_acc,
    const float* __restrict__ scal, float* __restrict__ out)
{
  __shared__ float sred[4];
  float v = 0.f;
  for (int i = threadIdx.x; i < N; i += 256) v += loss_acc[i];
  for (int o = 1; o < 64; o <<= 1) v += __shfl_xor(v, o, 64);
  if ((threadIdx.x & 63) == 0) sred[threadIdx.x >> 6] = v;
  __syncthreads();
  if (threadIdx.x == 0) out[0] = (sred[0] + sred[1] + sred[2] + sred[3]) / scal[0];
}

extern "C" void kernel_launch(void* const* d_in, const int* in_sizes, int n_in,
                              void* d_out, int out_size, void* d_ws, size_t ws_size,
                              hipStream_t stream)
{
  const float* x       = (const float*)d_in[0];
  const float* targets = (const float*)d_in[1];
  const int*   mask    = (const int*)d_in[2];
  const int*   ei      = (const int*)d_in[3];
  const float* W_msg   = (const float*)d_in[4];
  const float* b_msg   = (const float*)d_in[5];
  const float* W_mix   = (const float*)d_in[6];
  const float* b_mix   = (const float*)d_in[7];
  const float* W_ih    = (const float*)d_in[8];
  const float* W_hh    = (const float*)d_in[9];
  const float* b_ih    = (const float*)d_in[10];
  const float* b_hh    = (const float*)d_in[11];
  const float* W_read  = (const float*)d_in[12];
  const float* b_read  = (const float*)d_in[13];
  float* out = (float*)d_out;

  unsigned short* bufs  = (unsigned short*)d_ws;            // ring: 65 x [N][B][H] bf16 = 136 MB
  float* loss_acc       = (float*)(bufs + (size_t)(T + 1) * BNH);
  float* scal           = loss_acc + N;
  int* deg              = (int*)(scal + 16);
  int* row_ptr          = deg + N;
  int* cursor           = row_ptr + (N + 16);
  int* col_src          = cursor + N;
  int* bar              = col_src + E;                      // 8192 ints (32 KB)
  unsigned char* W_ihb  = (unsigned char*)(bar + 8192);     // fp8, 24 MB (16B aligned)
  unsigned char* W_hhb  = W_ihb + NWELEM;                   // fp8, 24 MB
  unsigned short* W_mixb = (unsigned short*)(W_hhb + NWELEM);
  unsigned short* W_msgb = W_mixb + 64 * 128;
  // total ws use ~185 MB

  init_kernel<<<1024, 256, 0, stream>>>(bufs, b_msg, loss_acc, scal, deg, bar);
  conv_kernel<<<8192, 256, 0, stream>>>(W_ih, W_hh, W_mix, W_msg, W_ihb, W_hhb, W_mixb, W_msgb);
  hist_kernel<<<E / 256, 256, 0, stream>>>(ei, deg);
  scan_kernel<<<1, 1024, 0, stream>>>(deg, row_ptr, cursor);
  fill_kernel<<<E / 256, 256, 0, stream>>>(ei, cursor, col_src);
  mask_kernel<<<512, 256, 0, stream>>>(mask, scal);

  // Always persistent (graph-capture safe: no runtime HIP queries).
  persist_kernel<<<NBLK, 256, 0, stream>>>(x, targets, mask,
                                           W_ihb, W_hhb, W_mixb, W_msgb,
                                           b_ih, b_hh, b_mix, b_msg, W_read, b_read,
                                           row_ptr, col_src, bufs, loss_acc, bar);

  final_kernel<<<1, 256, 0, stream>>>(loss_acc, scal, out);
}